// Round 18
// baseline (396.568 us; speedup 1.0000x reference)
//
#include <hip/hip_runtime.h>
#include <hip/hip_cooperative_groups.h>

namespace cg = cooperative_groups;

#define D_IN 128
#define D_OUT 64
#define DEG_STRIDE 16  // one counter per 64B line: kills atomic false sharing

__device__ __forceinline__ unsigned int pack_bf16x2(float a, float b) {
    unsigned int ua = __float_as_uint(a);
    unsigned int ub = __float_as_uint(b);
    ua = (ua + 0x7fffu + ((ua >> 16) & 1u)) >> 16;  // round-to-nearest-even
    ub = (ub + 0x7fffu + ((ub >> 16) & 1u)) >> 16;
    return ua | (ub << 16);
}

// ---------- fat kernel: node GEMM blocks ++ hist blocks (1 edge/thread) ----------
__global__ __launch_bounds__(256) void fat_kernel(
    const float* __restrict__ h, const float* __restrict__ W_fc,
    const float* __restrict__ W_attn, unsigned short* __restrict__ zb,
    float* __restrict__ as_, float* __restrict__ ad_,
    const int* __restrict__ dst, int* __restrict__ deg, int* __restrict__ rank,
    const float* __restrict__ W_eatt, const float* __restrict__ W_e2n,
    const float* __restrict__ W_edge, const float* __restrict__ attn_edge,
    float* __restrict__ M0buf, float* __restrict__ M1buf, float* __restrict__ cbuf,
    int N, int E, int gemmBlocks) {
    __shared__ float As[64][68];
    __shared__ float Bs[64][64];
    int bid = blockIdx.x;
    int t = threadIdx.x;
    if (bid < gemmBlocks) {
        int n0 = bid * 64;
        int tx = t & 15, ty = t >> 4;
        float acc[4][4] = {};
#pragma unroll
        for (int kh = 0; kh < 2; ++kh) {
            int kq = kh * 16;  // quad offset of this K-half
            for (int idx = t; idx < 1024; idx += 256) {
                int r = idx >> 4, q = idx & 15;
                float4 v = make_float4(0.f, 0.f, 0.f, 0.f);
                if (n0 + r < N) v = ((const float4*)h)[(size_t)(n0 + r) * 32 + kq + q];
                *(float4*)&As[r][q * 4] = v;
            }
            for (int idx = t; idx < 1024; idx += 256) {
                int r = idx >> 4, q = idx & 15;
                float4 v = ((const float4*)W_fc)[r * 32 + kq + q];
                *(float4*)&Bs[r][(q ^ ((r >> 2) & 15)) * 4] = v;  // XOR swizzle
            }
            __syncthreads();
#pragma unroll 2
            for (int k = 0; k < 64; k += 4) {
                int bq = (((k >> 2) ^ (tx & 15))) * 4;  // swizzled quad, j-invariant
                float4 a[4], b[4];
#pragma unroll
                for (int i = 0; i < 4; ++i) a[i] = *(const float4*)&As[ty * 4 + i][k];
#pragma unroll
                for (int j = 0; j < 4; ++j) b[j] = *(const float4*)&Bs[tx * 4 + j][bq];
#pragma unroll
                for (int i = 0; i < 4; ++i)
#pragma unroll
                    for (int j = 0; j < 4; ++j) {
                        acc[i][j] = fmaf(a[i].x, b[j].x, acc[i][j]);
                        acc[i][j] = fmaf(a[i].y, b[j].y, acc[i][j]);
                        acc[i][j] = fmaf(a[i].z, b[j].z, acc[i][j]);
                        acc[i][j] = fmaf(a[i].w, b[j].w, acc[i][j]);
                    }
            }
            __syncthreads();
        }
        float wa[4], wb[4];
#pragma unroll
        for (int j = 0; j < 4; ++j) {
            wa[j] = W_attn[tx * 4 + j];
            wb[j] = W_attn[64 + tx * 4 + j];
        }
#pragma unroll
        for (int i = 0; i < 4; ++i) {
            int n = n0 + ty * 4 + i;
            if (n >= N) break;
            uint2 zp;
            zp.x = pack_bf16x2(acc[i][0], acc[i][1]);
            zp.y = pack_bf16x2(acc[i][2], acc[i][3]);
            ((uint2*)(zb + (size_t)n * D_OUT))[tx] = zp;
            float pa = acc[i][0] * wa[0] + acc[i][1] * wa[1] + acc[i][2] * wa[2] + acc[i][3] * wa[3];
            float pb = acc[i][0] * wb[0] + acc[i][1] * wb[1] + acc[i][2] * wb[2] + acc[i][3] * wb[3];
            for (int off = 8; off; off >>= 1) {
                pa += __shfl_xor(pa, off);
                pb += __shfl_xor(pb, off);
            }
            if (tx == 0) {
                as_[n] = pa;
                ad_[n] = pb;
            }
        }
    } else {
        int hb = bid - gemmBlocks;
        if (hb == 0 && t < 64) {
            int d = t;
            M0buf[d] = W_e2n[d * 2 + 0] * W_eatt[0] + W_e2n[d * 2 + 1] * W_eatt[2];
            M1buf[d] = W_e2n[d * 2 + 0] * W_eatt[1] + W_e2n[d * 2 + 1] * W_eatt[3];
            float p0 = W_edge[d * 2 + 0] * attn_edge[d];
            float p1 = W_edge[d * 2 + 1] * attn_edge[d];
            for (int off = 32; off; off >>= 1) {
                p0 += __shfl_xor(p0, off);
                p1 += __shfl_xor(p1, off);
            }
            if (d == 0) {
                float t0 = W_attn[128] + p0;
                float t1 = W_attn[129] + p1;
                cbuf[0] = W_eatt[0] * t0 + W_eatt[2] * t1;
                cbuf[1] = W_eatt[1] * t0 + W_eatt[3] * t1;
            }
        }
        int i = hb * 256 + t;
        if (i < E) rank[i] = atomicAdd(&deg[(size_t)dst[i] * DEG_STRIDE], 1);
    }
}

// ---------- cooperative tail: scan (lookback) -> build -> fused ----------
__global__ void tail_kernel(const int* __restrict__ deg, int* __restrict__ row_start,
                            unsigned int* __restrict__ agg,
                            const float* __restrict__ e, const int* __restrict__ src,
                            const int* __restrict__ dst, const float* __restrict__ as_,
                            const float* __restrict__ ad_, const float* __restrict__ cbuf,
                            const int* __restrict__ rank, float4* __restrict__ pay,
                            const unsigned short* __restrict__ zb,
                            const float* __restrict__ M0buf, const float* __restrict__ M1buf,
                            float* __restrict__ hout, int nb, int N, int E) {
    cg::grid_group grid = cg::this_grid();
    __shared__ int wsum[4];
    __shared__ int spref;
    int t = threadIdx.x;
    int b = blockIdx.x;

    // ---- P1: chunk scan, 256 elems/chunk, release/acquire lookback ----
    if (b < nb) {
        int i = b * 256 + t;
        int v = (i < N) ? deg[(size_t)i * DEG_STRIDE] : 0;
        int lane = t & 63, w = t >> 6;
        int sc = v;
        for (int off = 1; off < 64; off <<= 1) {
            int x = __shfl_up(sc, off);
            if (lane >= off) sc += x;
        }
        if (lane == 63) wsum[w] = sc;
        __syncthreads();
        if (w == 0 && lane < 4) {
            int x = wsum[lane];
            for (int off = 1; off < 4; off <<= 1) {
                int y = __shfl_up(x, off);
                if (lane >= off) x += y;
            }
            wsum[lane] = x;
        }
        __syncthreads();
        int wofs = (w > 0) ? wsum[w - 1] : 0;
        int incl = wofs + sc;
        if (t == 255)
            __hip_atomic_store(&agg[b], 0x80000000u | (unsigned)incl, __ATOMIC_RELEASE,
                               __HIP_MEMORY_SCOPE_AGENT);
        if (t < 64) {
            int accp = 0;
            for (int j = t; j < b; j += 64) {
                unsigned x;
                do {
                    x = __hip_atomic_load(&agg[j], __ATOMIC_ACQUIRE,
                                          __HIP_MEMORY_SCOPE_AGENT);
                } while (!(x & 0x80000000u));
                accp += (int)(x & 0x7fffffffu);
            }
            for (int off = 32; off; off >>= 1) accp += __shfl_xor(accp, off);
            if (t == 0) spref = accp;
        }
        __syncthreads();
        if (i < N) row_start[i] = spref + incl - v;
        if (b == 0 && t == 0) row_start[N] = E;
    }
    grid.sync();

    // ---- P2: build CSR payload, grid-stride ----
    for (int i = b * 256 + t; i < E; i += gridDim.x * 256) {
        int si = src[i], di = dst[i];
        float2 ev = ((const float2*)e)[i];
        float a = as_[si] + ad_[di] + ev.x * cbuf[0] + ev.y * cbuf[1];
        float lg = a > 0.f ? a : 0.01f * a;
        float w = __expf(lg);  // no max subtraction: logits O(10) << 88
        int pos = row_start[di] + rank[i];
        pay[pos] = make_float4(w, __int_as_float(si), ev.x, ev.y);
    }
    grid.sync();

    // ---- P3: fused aggregation, grid-stride over node-quads ----
    int wv = t >> 6, l = t & 63;
    int g = l >> 3, q = l & 7;
    int nblk = (N + 3) >> 2;
    for (int vb = b; vb < nblk; vb += gridDim.x) {
        int n = vb * 4 + wv;
        if (n >= N) continue;
        int start = row_start[n], end = row_start[n + 1];
        float* orow = &hout[(size_t)n * D_OUT + q * 8];
        if (start == end) {
            if (g == 0) {
                *(float4*)orow = make_float4(0.f, 0.f, 0.f, 0.f);
                *(float4*)(orow + 4) = make_float4(0.f, 0.f, 0.f, 0.f);
            }
            continue;
        }
        float accv[8] = {};
        float s = 0.f, s0 = 0.f, s1 = 0.f;
        for (int base = start; base < end; base += 64) {
            int j = base + l;
            float w = 0.f, e0 = 0.f, e1 = 0.f;
            int sj = 0;
            if (j < end) {
                float4 P = pay[j];
                w = P.x;
                sj = __float_as_int(P.y);
                e0 = P.z;
                e1 = P.w;
            }
            s += w;
            s0 = fmaf(w, e0, s0);
            s1 = fmaf(w, e1, s1);
            int cnt = end - base;
            if (cnt > 64) cnt = 64;
            int iters = (cnt + 7) >> 3;
            for (int jj = 0; jj < iters; ++jj) {
                int srcl = jj * 8 + g;
                float wb = __shfl(w, srcl);  // lanes past cnt carry w=0
                int sb = __shfl(sj, srcl);
                uint4 zv = *(const uint4*)((const char*)zb + ((size_t)sb << 7) + (q << 4));
#pragma unroll
                for (int k = 0; k < 4; ++k) {
                    unsigned int u = (&zv.x)[k];
                    float lo = __uint_as_float(u << 16);
                    float hi = __uint_as_float(u & 0xffff0000u);
                    accv[2 * k] = fmaf(wb, lo, accv[2 * k]);
                    accv[2 * k + 1] = fmaf(wb, hi, accv[2 * k + 1]);
                }
            }
        }
#pragma unroll
        for (int off = 8; off <= 32; off <<= 1) {
#pragma unroll
            for (int k = 0; k < 8; ++k) accv[k] += __shfl_xor(accv[k], off);
        }
        for (int off = 32; off; off >>= 1) {
            s += __shfl_xor(s, off);
            s0 += __shfl_xor(s0, off);
            s1 += __shfl_xor(s1, off);
        }
        if (g == 0) {
            float inv = 1.f / s;
            float o[8];
#pragma unroll
            for (int k = 0; k < 8; ++k) {
                float m0 = M0buf[q * 8 + k];
                float m1 = M1buf[q * 8 + k];
                o[k] = (accv[k] + m0 * s0 + m1 * s1) * inv;
            }
            *(float4*)orow = make_float4(o[0], o[1], o[2], o[3]);
            *(float4*)(orow + 4) = make_float4(o[4], o[5], o[6], o[7]);
        }
    }
}

extern "C" void kernel_launch(void* const* d_in, const int* in_sizes, int n_in,
                              void* d_out, int out_size, void* d_ws, size_t ws_size,
                              hipStream_t stream) {
    const float* h = (const float*)d_in[0];
    const float* e = (const float*)d_in[1];
    const int* src = (const int*)d_in[2];
    const int* dst = (const int*)d_in[3];
    const float* W_fc = (const float*)d_in[4];
    const float* W_attn = (const float*)d_in[5];
    const float* W_eatt = (const float*)d_in[6];
    const float* W_e2n = (const float*)d_in[7];
    const float* W_edge = (const float*)d_in[8];
    const float* attn_edge = (const float*)d_in[9];
    float* hout = (float*)d_out;

    const int N = in_sizes[0] / D_IN;
    const int E = in_sizes[2];
    const int nb = (N + 255) / 256;  // tail scan chunks (256/block)
    const int gemmBlocks = (N + 63) / 64;
    const int histBlocks = (E + 255) / 256;

    // workspace layout (16B-aligned payload first)
    float4* pay = (float4*)d_ws;                      // E float4
    unsigned short* zb = (unsigned short*)(pay + E);  // N*64 bf16
    float* as_ = (float*)(zb + (size_t)N * 64);       // N
    float* ad_ = as_ + N;                             // N
    float* M0buf = ad_ + N;                           // 64
    float* M1buf = M0buf + 64;                        // 64
    float* cbuf = M1buf + 64;                         // 2
    int* deg = (int*)(cbuf + 2);                      // N*DEG_STRIDE (memset w/ agg)
    unsigned int* agg = (unsigned int*)(deg + (size_t)N * DEG_STRIDE);  // 256
    int* rank = (int*)(agg + 256);                    // E
    int* row_start = rank + E;                        // N+1

    (void)hipMemsetAsync(deg, 0, ((size_t)N * DEG_STRIDE + 256) * sizeof(int), stream);
    fat_kernel<<<gemmBlocks + histBlocks, 256, 0, stream>>>(
        h, W_fc, W_attn, zb, as_, ad_, dst, deg, rank,
        W_eatt, W_e2n, W_edge, attn_edge, M0buf, M1buf, cbuf, N, E, gemmBlocks);

    int blocksPerCU = 0;
    (void)hipOccupancyMaxActiveBlocksPerMultiprocessor(&blocksPerCU,
                                                       (const void*)tail_kernel, 256, 0);
    if (blocksPerCU < 1) blocksPerCU = 1;
    int grid = blocksPerCU * 256;  // 256 CUs on MI355X
    void* args[] = {(void*)&deg, (void*)&row_start, (void*)&agg, (void*)&e,
                    (void*)&src, (void*)&dst, (void*)&as_, (void*)&ad_,
                    (void*)&cbuf, (void*)&rank, (void*)&pay, (void*)&zb,
                    (void*)&M0buf, (void*)&M1buf, (void*)&hout,
                    (void*)&nb, (void*)&N, (void*)&E};
    (void)hipLaunchCooperativeKernel((const void*)tail_kernel, dim3(grid), dim3(256),
                                     args, 0, stream);
}

// Round 19
// 134.312 us; speedup vs baseline: 2.9526x; 2.9526x over previous
//
#include <hip/hip_runtime.h>

#define D_IN 128
#define D_OUT 64
#define SCAN_B 512
#define DEG_STRIDE 16  // one counter per 64B line: kills atomic false sharing

__device__ __forceinline__ unsigned int pack_bf16x2(float a, float b) {
    unsigned int ua = __float_as_uint(a);
    unsigned int ub = __float_as_uint(b);
    ua = (ua + 0x7fffu + ((ua >> 16) & 1u)) >> 16;  // round-to-nearest-even
    ub = (ub + 0x7fffu + ((ub >> 16) & 1u)) >> 16;
    return ua | (ub << 16);
}

// ---------- fat kernel: node GEMM blocks ++ hist blocks (1 edge/thread) ----------
// BK=32 -> 17.4KB LDS -> 8 blocks/CU (was 4): doubles co-resident hist waves.
__global__ __launch_bounds__(256) void fat_kernel(
    const float* __restrict__ h, const float* __restrict__ W_fc,
    const float* __restrict__ W_attn, unsigned short* __restrict__ zb,
    float* __restrict__ as_, float* __restrict__ ad_,
    const int* __restrict__ dst, int* __restrict__ deg, int* __restrict__ rank,
    const float* __restrict__ W_eatt, const float* __restrict__ W_e2n,
    const float* __restrict__ W_edge, const float* __restrict__ attn_edge,
    float* __restrict__ M0buf, float* __restrict__ M1buf, float* __restrict__ cbuf,
    int N, int E, int gemmBlocks) {
    __shared__ float As[64][36];  // 36 % 32 == 4: same conflict-free class as [68]
    __shared__ float Bs[64][32];
    int bid = blockIdx.x;
    int t = threadIdx.x;
    if (bid < gemmBlocks) {
        int n0 = bid * 64;
        int tx = t & 15, ty = t >> 4;
        float acc[4][4] = {};
#pragma unroll
        for (int kh = 0; kh < 4; ++kh) {
            int kq = kh * 8;  // quad offset of this K-quarter
            for (int idx = t; idx < 512; idx += 256) {
                int r = idx >> 3, q = idx & 7;
                float4 v = make_float4(0.f, 0.f, 0.f, 0.f);
                if (n0 + r < N) v = ((const float4*)h)[(size_t)(n0 + r) * 32 + kq + q];
                *(float4*)&As[r][q * 4] = v;
            }
            for (int idx = t; idx < 512; idx += 256) {
                int r = idx >> 3, q = idx & 7;
                float4 v = ((const float4*)W_fc)[r * 32 + kq + q];
                *(float4*)&Bs[r][(q ^ ((r >> 2) & 7)) * 4] = v;  // XOR swizzle
            }
            __syncthreads();
#pragma unroll
            for (int k = 0; k < 32; k += 4) {
                int bq = (((k >> 2) ^ (tx & 7))) * 4;  // swizzled quad, j-invariant
                float4 a[4], b[4];
#pragma unroll
                for (int i = 0; i < 4; ++i) a[i] = *(const float4*)&As[ty * 4 + i][k];
#pragma unroll
                for (int j = 0; j < 4; ++j) b[j] = *(const float4*)&Bs[tx * 4 + j][bq];
#pragma unroll
                for (int i = 0; i < 4; ++i)
#pragma unroll
                    for (int j = 0; j < 4; ++j) {
                        acc[i][j] = fmaf(a[i].x, b[j].x, acc[i][j]);
                        acc[i][j] = fmaf(a[i].y, b[j].y, acc[i][j]);
                        acc[i][j] = fmaf(a[i].z, b[j].z, acc[i][j]);
                        acc[i][j] = fmaf(a[i].w, b[j].w, acc[i][j]);
                    }
            }
            __syncthreads();
        }
        float wa[4], wb[4];
#pragma unroll
        for (int j = 0; j < 4; ++j) {
            wa[j] = W_attn[tx * 4 + j];
            wb[j] = W_attn[64 + tx * 4 + j];
        }
#pragma unroll
        for (int i = 0; i < 4; ++i) {
            int n = n0 + ty * 4 + i;
            if (n >= N) break;
            uint2 zp;
            zp.x = pack_bf16x2(acc[i][0], acc[i][1]);
            zp.y = pack_bf16x2(acc[i][2], acc[i][3]);
            ((uint2*)(zb + (size_t)n * D_OUT))[tx] = zp;
            float pa = acc[i][0] * wa[0] + acc[i][1] * wa[1] + acc[i][2] * wa[2] + acc[i][3] * wa[3];
            float pb = acc[i][0] * wb[0] + acc[i][1] * wb[1] + acc[i][2] * wb[2] + acc[i][3] * wb[3];
            for (int off = 8; off; off >>= 1) {
                pa += __shfl_xor(pa, off);
                pb += __shfl_xor(pb, off);
            }
            if (tx == 0) {
                as_[n] = pa;
                ad_[n] = pb;
            }
        }
    } else {
        int hb = bid - gemmBlocks;
        if (hb == 0 && t < 64) {
            int d = t;
            M0buf[d] = W_e2n[d * 2 + 0] * W_eatt[0] + W_e2n[d * 2 + 1] * W_eatt[2];
            M1buf[d] = W_e2n[d * 2 + 0] * W_eatt[1] + W_e2n[d * 2 + 1] * W_eatt[3];
            float p0 = W_edge[d * 2 + 0] * attn_edge[d];
            float p1 = W_edge[d * 2 + 1] * attn_edge[d];
            for (int off = 32; off; off >>= 1) {
                p0 += __shfl_xor(p0, off);
                p1 += __shfl_xor(p1, off);
            }
            if (d == 0) {
                float t0 = W_attn[128] + p0;
                float t1 = W_attn[129] + p1;
                cbuf[0] = W_eatt[0] * t0 + W_eatt[2] * t1;
                cbuf[1] = W_eatt[1] * t0 + W_eatt[3] * t1;
            }
        }
        int i = hb * 256 + t;
        if (i < E) rank[i] = atomicAdd(&deg[(size_t)dst[i] * DEG_STRIDE], 1);
    }
}

// ---------- single-pass scan: ticketed decoupled lookback ----------
__global__ void scan_kernel(const int* __restrict__ deg, int* __restrict__ row_start,
                            unsigned int* __restrict__ agg, int* __restrict__ ticket_ctr,
                            int nb, int N, int E) {
    __shared__ int wsum[8];
    __shared__ int sticket;
    __shared__ int spref;
    int t = threadIdx.x;
    if (t == 0) sticket = atomicAdd(ticket_ctr, 1);
    __syncthreads();
    int b = sticket;
    int i = b * SCAN_B + t;
    int v = (i < N) ? deg[(size_t)i * DEG_STRIDE] : 0;
    int lane = t & 63, w = t >> 6;
    int sc = v;
    for (int off = 1; off < 64; off <<= 1) {
        int x = __shfl_up(sc, off);
        if (lane >= off) sc += x;
    }
    if (lane == 63) wsum[w] = sc;
    __syncthreads();
    if (w == 0 && lane < 8) {
        int x = wsum[lane];
        for (int off = 1; off < 8; off <<= 1) {
            int y = __shfl_up(x, off);
            if (lane >= off) x += y;
        }
        wsum[lane] = x;
    }
    __syncthreads();
    int wofs = (w > 0) ? wsum[w - 1] : 0;
    int incl = wofs + sc;  // inclusive prefix within chunk
    if (t == SCAN_B - 1)
        __hip_atomic_store(&agg[b], 0x80000000u | (unsigned)incl, __ATOMIC_RELEASE,
                           __HIP_MEMORY_SCOPE_AGENT);
    if (t < 64) {
        int accp = 0;
        for (int j = t; j < b; j += 64) {
            unsigned x;
            do {
                x = __hip_atomic_load(&agg[j], __ATOMIC_ACQUIRE, __HIP_MEMORY_SCOPE_AGENT);
            } while (!(x & 0x80000000u));
            accp += (int)(x & 0x7fffffffu);
        }
        for (int off = 32; off; off >>= 1) accp += __shfl_xor(accp, off);
        if (t == 0) spref = accp;
    }
    __syncthreads();
    if (i < N) row_start[i] = spref + incl - v;
    if (b == 0 && t == 0) row_start[N] = E;
}

// ---------- build CSR payload {w, src, e0, e1}; fire-and-forget scatter ----------
__global__ void build_logit_kernel(const float* __restrict__ e,
                                   const int* __restrict__ src,
                                   const int* __restrict__ dst,
                                   const float* __restrict__ as_,
                                   const float* __restrict__ ad_,
                                   const float* __restrict__ cbuf,
                                   const int* __restrict__ row_start,
                                   const int* __restrict__ rank,
                                   float4* __restrict__ pay, int E) {
    int i = blockIdx.x * 256 + threadIdx.x;
    if (i >= E) return;
    int si = src[i], di = dst[i];
    float2 ev = ((const float2*)e)[i];
    float a = as_[si] + ad_[di] + ev.x * cbuf[0] + ev.y * cbuf[1];
    float lg = a > 0.f ? a : 0.01f * a;
    float w = __expf(lg);  // no max subtraction: logits O(10) << 88
    int pos = row_start[di] + rank[i];
    pay[pos] = make_float4(w, __int_as_float(si), ev.x, ev.y);
}

// ---------- fused aggregation: 8 edges/iter, bf16 z gather ----------
__global__ __launch_bounds__(256) void fused_kernel(const unsigned short* __restrict__ zb,
                                                    const float4* __restrict__ pay,
                                                    const int* __restrict__ row_start,
                                                    const float* __restrict__ M0buf,
                                                    const float* __restrict__ M1buf,
                                                    float* __restrict__ hout, int N) {
    int wv = threadIdx.x >> 6, l = threadIdx.x & 63;
    int n = blockIdx.x * 4 + wv;
    if (n >= N) return;
    int start = row_start[n], end = row_start[n + 1];
    int g = l >> 3, q = l & 7;
    float* orow = &hout[(size_t)n * D_OUT + q * 8];
    if (start == end) {
        if (g == 0) {
            *(float4*)orow = make_float4(0.f, 0.f, 0.f, 0.f);
            *(float4*)(orow + 4) = make_float4(0.f, 0.f, 0.f, 0.f);
        }
        return;
    }
    float accv[8] = {};
    float s = 0.f, s0 = 0.f, s1 = 0.f;
    for (int base = start; base < end; base += 64) {
        int j = base + l;
        float w = 0.f, e0 = 0.f, e1 = 0.f;
        int sj = 0;
        if (j < end) {
            float4 P = pay[j];
            w = P.x;
            sj = __float_as_int(P.y);
            e0 = P.z;
            e1 = P.w;
        }
        s += w;
        s0 = fmaf(w, e0, s0);
        s1 = fmaf(w, e1, s1);
        int cnt = end - base;
        if (cnt > 64) cnt = 64;
        int iters = (cnt + 7) >> 3;
        for (int jj = 0; jj < iters; ++jj) {
            int srcl = jj * 8 + g;
            float wb = __shfl(w, srcl);  // lanes past cnt carry w=0
            int sb = __shfl(sj, srcl);
            uint4 zv = *(const uint4*)((const char*)zb + ((size_t)sb << 7) + (q << 4));
#pragma unroll
            for (int k = 0; k < 4; ++k) {
                unsigned int u = (&zv.x)[k];
                float lo = __uint_as_float(u << 16);
                float hi = __uint_as_float(u & 0xffff0000u);
                accv[2 * k] = fmaf(wb, lo, accv[2 * k]);
                accv[2 * k + 1] = fmaf(wb, hi, accv[2 * k + 1]);
            }
        }
    }
#pragma unroll
    for (int off = 8; off <= 32; off <<= 1) {
#pragma unroll
        for (int k = 0; k < 8; ++k) accv[k] += __shfl_xor(accv[k], off);
    }
    for (int off = 32; off; off >>= 1) {
        s += __shfl_xor(s, off);
        s0 += __shfl_xor(s0, off);
        s1 += __shfl_xor(s1, off);
    }
    if (g == 0) {
        float inv = 1.f / s;
        float o[8];
#pragma unroll
        for (int k = 0; k < 8; ++k) {
            float m0 = M0buf[q * 8 + k];
            float m1 = M1buf[q * 8 + k];
            o[k] = (accv[k] + m0 * s0 + m1 * s1) * inv;
        }
        *(float4*)orow = make_float4(o[0], o[1], o[2], o[3]);
        *(float4*)(orow + 4) = make_float4(o[4], o[5], o[6], o[7]);
    }
}

extern "C" void kernel_launch(void* const* d_in, const int* in_sizes, int n_in,
                              void* d_out, int out_size, void* d_ws, size_t ws_size,
                              hipStream_t stream) {
    const float* h = (const float*)d_in[0];
    const float* e = (const float*)d_in[1];
    const int* src = (const int*)d_in[2];
    const int* dst = (const int*)d_in[3];
    const float* W_fc = (const float*)d_in[4];
    const float* W_attn = (const float*)d_in[5];
    const float* W_eatt = (const float*)d_in[6];
    const float* W_e2n = (const float*)d_in[7];
    const float* W_edge = (const float*)d_in[8];
    const float* attn_edge = (const float*)d_in[9];
    float* hout = (float*)d_out;

    const int N = in_sizes[0] / D_IN;
    const int E = in_sizes[2];
    const int nb = (N + SCAN_B - 1) / SCAN_B;
    const int gemmBlocks = (N + 63) / 64;
    const int histBlocks = (E + 255) / 256;

    // workspace layout (16B-aligned payload first)
    float4* pay = (float4*)d_ws;                      // E float4
    unsigned short* zb = (unsigned short*)(pay + E);  // N*64 bf16
    float* as_ = (float*)(zb + (size_t)N * 64);       // N
    float* ad_ = as_ + N;                             // N
    float* M0buf = ad_ + N;                           // 64
    float* M1buf = M0buf + 64;                        // 64
    float* cbuf = M1buf + 64;                         // 2
    int* deg = (int*)(cbuf + 2);                      // N*DEG_STRIDE (memset w/ agg+ticket)
    unsigned int* agg = (unsigned int*)(deg + (size_t)N * DEG_STRIDE);  // 128
    int* ticket_ctr = (int*)(agg + 128);              // 1
    int* rank = ticket_ctr + 1;                       // E
    int* row_start = rank + E;                        // N+1

    (void)hipMemsetAsync(deg, 0, ((size_t)N * DEG_STRIDE + 129) * sizeof(int), stream);
    fat_kernel<<<gemmBlocks + histBlocks, 256, 0, stream>>>(
        h, W_fc, W_attn, zb, as_, ad_, dst, deg, rank,
        W_eatt, W_e2n, W_edge, attn_edge, M0buf, M1buf, cbuf, N, E, gemmBlocks);
    scan_kernel<<<nb, SCAN_B, 0, stream>>>(deg, row_start, agg, ticket_ctr, nb, N, E);
    build_logit_kernel<<<(E + 255) / 256, 256, 0, stream>>>(e, src, dst, as_, ad_, cbuf,
                                                            row_start, rank, pay, E);
    fused_kernel<<<(N + 3) / 4, 256, 0, stream>>>(zb, pay, row_start, M0buf, M1buf, hout, N);
}

// Round 20
// 103.761 us; speedup vs baseline: 3.8220x; 1.2944x over previous
//
#include <hip/hip_runtime.h>

#define D_IN 128
#define D_OUT 64
#define SCAN_B 512
#define DEG_STRIDE 16  // one counter per 64B line: kills atomic false sharing

__device__ __forceinline__ unsigned int pack_bf16x2(float a, float b) {
    unsigned int ua = __float_as_uint(a);
    unsigned int ub = __float_as_uint(b);
    ua = (ua + 0x7fffu + ((ua >> 16) & 1u)) >> 16;  // round-to-nearest-even
    ub = (ub + 0x7fffu + ((ub >> 16) & 1u)) >> 16;
    return ua | (ub << 16);
}

// ---------- fat kernel: node GEMM blocks ++ hist blocks (1 edge/thread) ----------
// BK=64 (round-17 proven config: VGPR~60, conflicts ~0, fat < 42us).
// As[64][68]: pad -> ty-broadcast reads on distinct banks (free).
// Bs[64][64]: XOR swizzle quad^((r>>2)&15); read quad (k>>2)^(tx&15), j-invariant.
__global__ __launch_bounds__(256) void fat_kernel(
    const float* __restrict__ h, const float* __restrict__ W_fc,
    const float* __restrict__ W_attn, unsigned short* __restrict__ zb,
    float* __restrict__ as_, float* __restrict__ ad_,
    const int* __restrict__ dst, int* __restrict__ deg, int* __restrict__ rank,
    const float* __restrict__ W_eatt, const float* __restrict__ W_e2n,
    const float* __restrict__ W_edge, const float* __restrict__ attn_edge,
    float* __restrict__ M0buf, float* __restrict__ M1buf, float* __restrict__ cbuf,
    int N, int E, int gemmBlocks) {
    __shared__ float As[64][68];
    __shared__ float Bs[64][64];
    int bid = blockIdx.x;
    int t = threadIdx.x;
    if (bid < gemmBlocks) {
        int n0 = bid * 64;
        int tx = t & 15, ty = t >> 4;
        float acc[4][4] = {};
        for (int kh = 0; kh < 2; ++kh) {  // no unroll pragma: keep VGPR low
            int kq = kh * 16;  // quad offset of this K-half
            for (int idx = t; idx < 1024; idx += 256) {
                int r = idx >> 4, q = idx & 15;
                float4 v = make_float4(0.f, 0.f, 0.f, 0.f);
                if (n0 + r < N) v = ((const float4*)h)[(size_t)(n0 + r) * 32 + kq + q];
                *(float4*)&As[r][q * 4] = v;
            }
            for (int idx = t; idx < 1024; idx += 256) {
                int r = idx >> 4, q = idx & 15;
                float4 v = ((const float4*)W_fc)[r * 32 + kq + q];
                *(float4*)&Bs[r][(q ^ ((r >> 2) & 15)) * 4] = v;  // XOR swizzle
            }
            __syncthreads();
#pragma unroll 2
            for (int k = 0; k < 64; k += 4) {
                int bq = (((k >> 2) ^ (tx & 15))) * 4;  // swizzled quad, j-invariant
                float4 a[4], b[4];
#pragma unroll
                for (int i = 0; i < 4; ++i) a[i] = *(const float4*)&As[ty * 4 + i][k];
#pragma unroll
                for (int j = 0; j < 4; ++j) b[j] = *(const float4*)&Bs[tx * 4 + j][bq];
#pragma unroll
                for (int i = 0; i < 4; ++i)
#pragma unroll
                    for (int j = 0; j < 4; ++j) {
                        acc[i][j] = fmaf(a[i].x, b[j].x, acc[i][j]);
                        acc[i][j] = fmaf(a[i].y, b[j].y, acc[i][j]);
                        acc[i][j] = fmaf(a[i].z, b[j].z, acc[i][j]);
                        acc[i][j] = fmaf(a[i].w, b[j].w, acc[i][j]);
                    }
            }
            __syncthreads();
        }
        float wa[4], wb[4];
#pragma unroll
        for (int j = 0; j < 4; ++j) {
            wa[j] = W_attn[tx * 4 + j];
            wb[j] = W_attn[64 + tx * 4 + j];
        }
#pragma unroll
        for (int i = 0; i < 4; ++i) {
            int n = n0 + ty * 4 + i;
            if (n >= N) break;
            uint2 zp;
            zp.x = pack_bf16x2(acc[i][0], acc[i][1]);
            zp.y = pack_bf16x2(acc[i][2], acc[i][3]);
            ((uint2*)(zb + (size_t)n * D_OUT))[tx] = zp;
            float pa = acc[i][0] * wa[0] + acc[i][1] * wa[1] + acc[i][2] * wa[2] + acc[i][3] * wa[3];
            float pb = acc[i][0] * wb[0] + acc[i][1] * wb[1] + acc[i][2] * wb[2] + acc[i][3] * wb[3];
            for (int off = 8; off; off >>= 1) {
                pa += __shfl_xor(pa, off);
                pb += __shfl_xor(pb, off);
            }
            if (tx == 0) {
                as_[n] = pa;
                ad_[n] = pb;
            }
        }
    } else {
        int hb = bid - gemmBlocks;
        if (hb == 0 && t < 64) {
            int d = t;
            M0buf[d] = W_e2n[d * 2 + 0] * W_eatt[0] + W_e2n[d * 2 + 1] * W_eatt[2];
            M1buf[d] = W_e2n[d * 2 + 0] * W_eatt[1] + W_e2n[d * 2 + 1] * W_eatt[3];
            float p0 = W_edge[d * 2 + 0] * attn_edge[d];
            float p1 = W_edge[d * 2 + 1] * attn_edge[d];
            for (int off = 32; off; off >>= 1) {
                p0 += __shfl_xor(p0, off);
                p1 += __shfl_xor(p1, off);
            }
            if (d == 0) {
                float t0 = W_attn[128] + p0;
                float t1 = W_attn[129] + p1;
                cbuf[0] = W_eatt[0] * t0 + W_eatt[2] * t1;
                cbuf[1] = W_eatt[1] * t0 + W_eatt[3] * t1;
            }
        }
        int i = hb * 256 + t;
        if (i < E) rank[i] = atomicAdd(&deg[(size_t)dst[i] * DEG_STRIDE], 1);
    }
}

// ---------- single-pass scan: ticketed decoupled lookback ----------
__global__ void scan_kernel(const int* __restrict__ deg, int* __restrict__ row_start,
                            unsigned int* __restrict__ agg, int* __restrict__ ticket_ctr,
                            int nb, int N, int E) {
    __shared__ int wsum[8];
    __shared__ int sticket;
    __shared__ int spref;
    int t = threadIdx.x;
    if (t == 0) sticket = atomicAdd(ticket_ctr, 1);
    __syncthreads();
    int b = sticket;
    int i = b * SCAN_B + t;
    int v = (i < N) ? deg[(size_t)i * DEG_STRIDE] : 0;
    int lane = t & 63, w = t >> 6;
    int sc = v;
    for (int off = 1; off < 64; off <<= 1) {
        int x = __shfl_up(sc, off);
        if (lane >= off) sc += x;
    }
    if (lane == 63) wsum[w] = sc;
    __syncthreads();
    if (w == 0 && lane < 8) {
        int x = wsum[lane];
        for (int off = 1; off < 8; off <<= 1) {
            int y = __shfl_up(x, off);
            if (lane >= off) x += y;
        }
        wsum[lane] = x;
    }
    __syncthreads();
    int wofs = (w > 0) ? wsum[w - 1] : 0;
    int incl = wofs + sc;  // inclusive prefix within chunk
    if (t == SCAN_B - 1)
        __hip_atomic_store(&agg[b], 0x80000000u | (unsigned)incl, __ATOMIC_RELEASE,
                           __HIP_MEMORY_SCOPE_AGENT);
    if (t < 64) {
        int accp = 0;
        for (int j = t; j < b; j += 64) {
            unsigned x;
            do {
                x = __hip_atomic_load(&agg[j], __ATOMIC_ACQUIRE, __HIP_MEMORY_SCOPE_AGENT);
            } while (!(x & 0x80000000u));
            accp += (int)(x & 0x7fffffffu);
        }
        for (int off = 32; off; off >>= 1) accp += __shfl_xor(accp, off);
        if (t == 0) spref = accp;
    }
    __syncthreads();
    if (i < N) row_start[i] = spref + incl - v;
    if (b == 0 && t == 0) row_start[N] = E;
}

// ---------- build CSR payload {w, src, e0, e1}; fire-and-forget scatter ----------
__global__ void build_logit_kernel(const float* __restrict__ e,
                                   const int* __restrict__ src,
                                   const int* __restrict__ dst,
                                   const float* __restrict__ as_,
                                   const float* __restrict__ ad_,
                                   const float* __restrict__ cbuf,
                                   const int* __restrict__ row_start,
                                   const int* __restrict__ rank,
                                   float4* __restrict__ pay, int E) {
    int i = blockIdx.x * 256 + threadIdx.x;
    if (i >= E) return;
    int si = src[i], di = dst[i];
    float2 ev = ((const float2*)e)[i];
    float a = as_[si] + ad_[di] + ev.x * cbuf[0] + ev.y * cbuf[1];
    float lg = a > 0.f ? a : 0.01f * a;
    float w = __expf(lg);  // no max subtraction: logits O(10) << 88
    int pos = row_start[di] + rank[i];
    pay[pos] = make_float4(w, __int_as_float(si), ev.x, ev.y);
}

// ---------- fused aggregation: 8 edges/iter, bf16 z gather ----------
__global__ __launch_bounds__(256) void fused_kernel(const unsigned short* __restrict__ zb,
                                                    const float4* __restrict__ pay,
                                                    const int* __restrict__ row_start,
                                                    const float* __restrict__ M0buf,
                                                    const float* __restrict__ M1buf,
                                                    float* __restrict__ hout, int N) {
    int wv = threadIdx.x >> 6, l = threadIdx.x & 63;
    int n = blockIdx.x * 4 + wv;
    if (n >= N) return;
    int start = row_start[n], end = row_start[n + 1];
    int g = l >> 3, q = l & 7;
    float* orow = &hout[(size_t)n * D_OUT + q * 8];
    if (start == end) {
        if (g == 0) {
            *(float4*)orow = make_float4(0.f, 0.f, 0.f, 0.f);
            *(float4*)(orow + 4) = make_float4(0.f, 0.f, 0.f, 0.f);
        }
        return;
    }
    float accv[8] = {};
    float s = 0.f, s0 = 0.f, s1 = 0.f;
    for (int base = start; base < end; base += 64) {
        int j = base + l;
        float w = 0.f, e0 = 0.f, e1 = 0.f;
        int sj = 0;
        if (j < end) {
            float4 P = pay[j];
            w = P.x;
            sj = __float_as_int(P.y);
            e0 = P.z;
            e1 = P.w;
        }
        s += w;
        s0 = fmaf(w, e0, s0);
        s1 = fmaf(w, e1, s1);
        int cnt = end - base;
        if (cnt > 64) cnt = 64;
        int iters = (cnt + 7) >> 3;
        for (int jj = 0; jj < iters; ++jj) {
            int srcl = jj * 8 + g;
            float wb = __shfl(w, srcl);  // lanes past cnt carry w=0
            int sb = __shfl(sj, srcl);
            uint4 zv = *(const uint4*)((const char*)zb + ((size_t)sb << 7) + (q << 4));
#pragma unroll
            for (int k = 0; k < 4; ++k) {
                unsigned int u = (&zv.x)[k];
                float lo = __uint_as_float(u << 16);
                float hi = __uint_as_float(u & 0xffff0000u);
                accv[2 * k] = fmaf(wb, lo, accv[2 * k]);
                accv[2 * k + 1] = fmaf(wb, hi, accv[2 * k + 1]);
            }
        }
    }
#pragma unroll
    for (int off = 8; off <= 32; off <<= 1) {
#pragma unroll
        for (int k = 0; k < 8; ++k) accv[k] += __shfl_xor(accv[k], off);
    }
    for (int off = 32; off; off >>= 1) {
        s += __shfl_xor(s, off);
        s0 += __shfl_xor(s0, off);
        s1 += __shfl_xor(s1, off);
    }
    if (g == 0) {
        float inv = 1.f / s;
        float o[8];
#pragma unroll
        for (int k = 0; k < 8; ++k) {
            float m0 = M0buf[q * 8 + k];
            float m1 = M1buf[q * 8 + k];
            o[k] = (accv[k] + m0 * s0 + m1 * s1) * inv;
        }
        *(float4*)orow = make_float4(o[0], o[1], o[2], o[3]);
        *(float4*)(orow + 4) = make_float4(o[4], o[5], o[6], o[7]);
    }
}

extern "C" void kernel_launch(void* const* d_in, const int* in_sizes, int n_in,
                              void* d_out, int out_size, void* d_ws, size_t ws_size,
                              hipStream_t stream) {
    const float* h = (const float*)d_in[0];
    const float* e = (const float*)d_in[1];
    const int* src = (const int*)d_in[2];
    const int* dst = (const int*)d_in[3];
    const float* W_fc = (const float*)d_in[4];
    const float* W_attn = (const float*)d_in[5];
    const float* W_eatt = (const float*)d_in[6];
    const float* W_e2n = (const float*)d_in[7];
    const float* W_edge = (const float*)d_in[8];
    const float* attn_edge = (const float*)d_in[9];
    float* hout = (float*)d_out;

    const int N = in_sizes[0] / D_IN;
    const int E = in_sizes[2];
    const int nb = (N + SCAN_B - 1) / SCAN_B;
    const int gemmBlocks = (N + 63) / 64;
    const int histBlocks = (E + 255) / 256;

    // workspace layout (16B-aligned payload first)
    float4* pay = (float4*)d_ws;                      // E float4
    unsigned short* zb = (unsigned short*)(pay + E);  // N*64 bf16
    float* as_ = (float*)(zb + (size_t)N * 64);       // N
    float* ad_ = as_ + N;                             // N
    float* M0buf = ad_ + N;                           // 64
    float* M1buf = M0buf + 64;                        // 64
    float* cbuf = M1buf + 64;                         // 2
    int* deg = (int*)(cbuf + 2);                      // N*DEG_STRIDE (memset w/ agg+ticket)
    unsigned int* agg = (unsigned int*)(deg + (size_t)N * DEG_STRIDE);  // 128
    int* ticket_ctr = (int*)(agg + 128);              // 1
    int* rank = ticket_ctr + 1;                       // E
    int* row_start = rank + E;                        // N+1

    (void)hipMemsetAsync(deg, 0, ((size_t)N * DEG_STRIDE + 129) * sizeof(int), stream);
    fat_kernel<<<gemmBlocks + histBlocks, 256, 0, stream>>>(
        h, W_fc, W_attn, zb, as_, ad_, dst, deg, rank,
        W_eatt, W_e2n, W_edge, attn_edge, M0buf, M1buf, cbuf, N, E, gemmBlocks);
    scan_kernel<<<nb, SCAN_B, 0, stream>>>(deg, row_start, agg, ticket_ctr, nb, N, E);
    build_logit_kernel<<<(E + 255) / 256, 256, 0, stream>>>(e, src, dst, as_, ad_, cbuf,
                                                            row_start, rank, pay, E);
    fused_kernel<<<(N + 3) / 4, 256, 0, stream>>>(zb, pay, row_start, M0buf, M1buf, hout, N);
}